// Round 14
// baseline (417.094 us; speedup 1.0000x reference)
//
#include <hip/hip_runtime.h>
#include <math.h>

// Bahdanau attention: B=32, T=2048, D=512, Q=512, fp32.
// out = [score (B*T), weights (B*T), expectation (B*D)] concatenated.
// Masked positions: finite sentinel -1e30 (ref has -inf; |inf diff| <= inf thr,
// exp underflows to 0 identically).
//
// R14 = R13 + (a) phase-staggered K-loop start per block (kc0 = 4*hash):
// co-resident blocks were phase-locked (all MFMA together, all stall
// together -> MfmaUtil pinned at the 2-phase ceiling ~26%); K-sum is
// order-invariant so blocks can rotate through kc in different phases.
// (b) s_setprio(1) around the MFMA cluster (pays only with phase diversity).
// (c) X-prefetch issued before converts -> B-consume wait is counted
// vmcnt(8), X stays in flight across the barrier.

#define TPB 256
constexpr int B = 32, T = 2048, D = 512, Qd = 512;
constexpr int NROW = B * T;
#define NEG_SENTINEL (-1e30f)

typedef __attribute__((ext_vector_type(8))) short bf16x8;
typedef __attribute__((ext_vector_type(4))) float f32x4;

// LDS-only barrier: ds ops drained, vmem stays in flight.
__device__ __forceinline__ void lds_barrier() {
    asm volatile("s_waitcnt lgkmcnt(0)" ::: "memory");
    __builtin_amdgcn_s_barrier();
}

// HW packed fp32->bf16 RNE: result.lo16 = bf16(a), result.hi16 = bf16(b)
__device__ __forceinline__ unsigned cvtpk(float a, float b) {
    unsigned r;
    asm("v_cvt_pk_bf16_f32 %0, %1, %2" : "=v"(r) : "v"(a), "v"(b));
    return r;
}
// split two floats into packed-hi (return) and packed-lo bf16 pairs
__device__ __forceinline__ unsigned packsplit(float f0, float f1, unsigned& lopack) {
    unsigned hp = cvtpk(f0, f1);
    float h0 = __builtin_bit_cast(float, hp << 16);
    float h1 = __builtin_bit_cast(float, hp & 0xFFFF0000u);
    lopack = cvtpk(f0 - h0, f1 - h1);
    return hp;
}
__device__ __forceinline__ void cvt8(const float4 a, const float4 b, uint4& hi, uint4& lo) {
    hi.x = packsplit(a.x, a.y, lo.x);
    hi.y = packsplit(a.z, a.w, lo.y);
    hi.z = packsplit(b.x, b.y, lo.z);
    hi.w = packsplit(b.z, b.w, lo.w);
}
// fast tanh: saturating exp form, |err| ~ 1e-7
__device__ __forceinline__ float fast_tanh(float x) {
    float a = fabsf(x);
    float e = __expf(-2.f * a);
    float t = (1.f - e) / (1.f + e);
    return copysignf(t, x);
}

// ---------------------------------------------------------------- K1: uq[b][e]
__global__ void k_uq(const float* __restrict__ query, const float* __restrict__ u,
                     float* __restrict__ uq) {
    int b = blockIdx.x;
    __shared__ float q_s[Qd];
    for (int i = threadIdx.x; i < Qd; i += TPB) q_s[i] = query[b * Qd + i];
    __syncthreads();
    for (int e = threadIdx.x; e < D; e += TPB) {
        const float4* urow = (const float4*)(u + (size_t)e * Qd);
        float acc = 0.f;
        for (int q4 = 0; q4 < Qd / 4; ++q4) {
            float4 uu = urow[q4];
            float4 qq = *(const float4*)(q_s + q4 * 4);
            acc += uu.x * qq.x + uu.y * qq.y + uu.z * qq.z + uu.w * qq.w;
        }
        uq[b * D + e] = acc;
    }
}

// ---------------------------------------------------------------- K2: W -> split-bf16 fragment layout
// idx16 = ((nt*16 + kc)*8 + cb)*64 + hi4*16 + lo16
//   e = nt*128 + cb*16 + lo16, d = kc*32 + hi4*8 .. +8
__global__ void k_convW(const float* __restrict__ W,
                        uint4* __restrict__ WhF, uint4* __restrict__ WlF) {
    const int g = blockIdx.x * 256 + threadIdx.x;   // 0..32767
    const int e = g >> 6, s = g & 63;               // d0 = s*8
    const float4* src = (const float4*)(W + (size_t)e * D + s * 8);
    float4 a = src[0], bq = src[1];
    uint4 hi, lo;
    cvt8(a, bq, hi, lo);
    const int nt = e >> 7, cb = (e >> 4) & 7, lo16 = e & 15;
    const int kc = s >> 2, hi4 = s & 3;
    const size_t idx = ((size_t)(nt * 16 + kc) * 8 + cb) * 64 + hi4 * 16 + lo16;
    WhF[idx] = hi;
    WlF[idx] = lo;
}

// ---------------------------------------------------------------- K3: split-bf16 MFMA GEMM + fused tanh*v
// Block tile 128x128, BK=32, 4 waves (2m x 2n), wave 64x64 = 4x4 frags of
// 16x16x32, 3 products in fp32 acc. A: regs -> cvt_pk -> LDS double-buffer,
// one LDS-only barrier per K-step. B: preconverted frag-layout, global->reg
// (L2-resident). 4 blocks/CU. K-loop start phase-staggered per block.
__global__ __launch_bounds__(256, 4) void k_gemm(
    const float* __restrict__ X,
    const uint4* __restrict__ WhF,
    const uint4* __restrict__ WlF,
    const float* __restrict__ v,
    const float* __restrict__ uqg,
    float* __restrict__ partialS)   // [4][NROW]
{
    __shared__ uint4 Ah[2][4 * 128], Al[2][4 * 128];   // 32 KB
    __shared__ float scr[2][128];

    // XCD-bijective swizzle (2048 % 8 == 0)
    const int gidx = blockIdx.x;
    const int logical = (gidx & 7) * 256 + (gidx >> 3);
    const int mt = logical >> 2, nt = logical & 3;
    const int row0 = mt * 128, e0 = nt * 128;
    const int b = row0 >> 11;

    // K-phase stagger: robust to contiguous OR stride-256 co-residency.
    const int kc0 = (((gidx & 3) ^ ((gidx >> 8) & 3))) * 4;

    const int tid = threadIdx.x, lane = tid & 63, wid = tid >> 6;
    const int wm = wid >> 1, wn = wid & 1;
    const int lo16 = lane & 15, hi4 = lane >> 4;
    const int arow = tid & 127, akh = tid >> 7;

    const float4* Xg = (const float4*)(X + (size_t)(row0 + arow) * D + akh * 16);
    const uint4* WhB = WhF + ((size_t)nt * 16) * 8 * 64 + (wn * 4) * 64 + lane;
    const uint4* WlB = WlF + ((size_t)nt * 16) * 8 * 64 + (wn * 4) * 64 + lane;

    f32x4 acc[4][4];
#pragma unroll
    for (int i = 0; i < 4; ++i)
#pragma unroll
        for (int j = 0; j < 4; ++j) acc[i][j] = (f32x4){0.f, 0.f, 0.f, 0.f};

    // prologue: X(kc0)->xr[0], X(kc0+1)->xr[1]; convert X(kc0) -> buf0
    float4 xr[2][4];
#pragma unroll
    for (int i = 0; i < 4; ++i) xr[0][i] = Xg[kc0 * 8 + i];
    {
        const int k1 = ((kc0 + 1) & 15) * 8;
#pragma unroll
        for (int i = 0; i < 4; ++i) xr[1][i] = Xg[k1 + i];
    }
    {
        uint4 hp, lp;
        cvt8(xr[0][0], xr[0][1], hp, lp);
        Ah[0][(akh * 2 + 0) * 128 + arow] = hp;
        Al[0][(akh * 2 + 0) * 128 + arow] = lp;
        cvt8(xr[0][2], xr[0][3], hp, lp);
        Ah[0][(akh * 2 + 1) * 128 + arow] = hp;
        Al[0][(akh * 2 + 1) * 128 + arow] = lp;
    }

#pragma unroll
    for (int it = 0; it < 16; ++it) {
        const int kc = (kc0 + it) & 15;
        const int cur = it & 1, nxt = cur ^ 1;
        lds_barrier();   // buf[cur] visible; vmem stays in flight

        // B fragment loads for kc -- issued FIRST (oldest in vmem queue)
        uint4 bhr[4], blr[4];
        {
            const uint4* wh = WhB + (size_t)kc * 8 * 64;
            const uint4* wl = WlB + (size_t)kc * 8 * 64;
#pragma unroll
            for (int fc = 0; fc < 4; ++fc) {
                bhr[fc] = wh[fc * 64];
                blr[fc] = wl[fc * 64];
            }
        }
        // X prefetch for it+2 (issued after B -> B-wait is counted, X flies on)
        if (it + 2 < 16) {
            const int kp = ((kc0 + it + 2) & 15) * 8;
#pragma unroll
            for (int i = 0; i < 4; ++i) xr[cur][i] = Xg[kp + i];
        }

        // convert X(it+1) (loaded >=1 iter ago) -> buf[nxt]
        if (it + 1 < 16) {
            uint4 hp, lp;
            cvt8(xr[nxt][0], xr[nxt][1], hp, lp);
            Ah[nxt][(akh * 2 + 0) * 128 + arow] = hp;
            Al[nxt][(akh * 2 + 0) * 128 + arow] = lp;
            cvt8(xr[nxt][2], xr[nxt][3], hp, lp);
            Ah[nxt][(akh * 2 + 1) * 128 + arow] = hp;
            Al[nxt][(akh * 2 + 1) * 128 + arow] = lp;
        }

        // A fragments from buf[cur]
        bf16x8 aH[4], aL[4];
#pragma unroll
        for (int fr = 0; fr < 4; ++fr) {
            const int idx = hi4 * 128 + wm * 64 + fr * 16 + lo16;
            aH[fr] = __builtin_bit_cast(bf16x8, Ah[cur][idx]);
            aL[fr] = __builtin_bit_cast(bf16x8, Al[cur][idx]);
        }

        __builtin_amdgcn_s_setprio(1);
#pragma unroll
        for (int fc = 0; fc < 4; ++fc) {
            const bf16x8 bH = __builtin_bit_cast(bf16x8, bhr[fc]);
            const bf16x8 bL = __builtin_bit_cast(bf16x8, blr[fc]);
#pragma unroll
            for (int fr = 0; fr < 4; ++fr) {
                acc[fr][fc] = __builtin_amdgcn_mfma_f32_16x16x32_bf16(aH[fr], bH, acc[fr][fc], 0, 0, 0);
                acc[fr][fc] = __builtin_amdgcn_mfma_f32_16x16x32_bf16(aH[fr], bL, acc[fr][fc], 0, 0, 0);
                acc[fr][fc] = __builtin_amdgcn_mfma_f32_16x16x32_bf16(aL[fr], bH, acc[fr][fc], 0, 0, 0);
            }
        }
        __builtin_amdgcn_s_setprio(0);
    }

    // ---- epilogue: p[row] = sum_col tanh(acc + uq[col]) * v[col]
    const int colbase = e0 + wn * 64;
#pragma unroll
    for (int fr = 0; fr < 4; ++fr) {
        float ps[4] = {0.f, 0.f, 0.f, 0.f};
#pragma unroll
        for (int fc = 0; fc < 4; ++fc) {
            const int col = colbase + fc * 16 + lo16;
            const float uqc = uqg[b * D + col];
            const float vc  = v[col];
#pragma unroll
            for (int i = 0; i < 4; ++i)
                ps[i] += fast_tanh(acc[fr][fc][i] + uqc) * vc;
        }
#pragma unroll
        for (int i = 0; i < 4; ++i) {
            float p = ps[i];
#pragma unroll
            for (int off = 8; off >= 1; off >>= 1) p += __shfl_xor(p, off, 16);
            if (lo16 == 0) scr[wn][wm * 64 + fr * 16 + hi4 * 4 + i] = p;
        }
    }
    __syncthreads();
    if (tid < 128)
        partialS[(size_t)nt * NROW + row0 + tid] = scr[0][tid] + scr[1][tid];
}

// ---------------------------------------------------------------- K4: combine 4 partials + mask
__global__ void k_combine(const float* __restrict__ partialS,
                          const int* __restrict__ lengths,
                          float* __restrict__ score) {
    const int i = blockIdx.x * TPB + threadIdx.x;
    const int b = i >> 11, t = i & (T - 1);
    float s = partialS[i] + partialS[NROW + i] + partialS[2 * NROW + i] + partialS[3 * NROW + i];
    score[i] = (t < lengths[b]) ? s : NEG_SENTINEL;
}

// ---------------------------------------------------------------- K5: softmax over t per batch
__global__ void k_softmax(const float* __restrict__ score, float* __restrict__ weights) {
    const int b = blockIdx.x;
    const float* s = score + (size_t)b * T;
    float m = -INFINITY;
    for (int t = threadIdx.x; t < T; t += TPB) m = fmaxf(m, s[t]);
#pragma unroll
    for (int off = 32; off >= 1; off >>= 1) m = fmaxf(m, __shfl_xor(m, off, 64));
    __shared__ float redm[4];
    if ((threadIdx.x & 63) == 0) redm[threadIdx.x >> 6] = m;
    __syncthreads();
    m = fmaxf(fmaxf(redm[0], redm[1]), fmaxf(redm[2], redm[3]));

    float sum = 0.f;
    for (int t = threadIdx.x; t < T; t += TPB) sum += __expf(s[t] - m);
#pragma unroll
    for (int off = 32; off >= 1; off >>= 1) sum += __shfl_xor(sum, off, 64);
    __shared__ float reds[4];
    if ((threadIdx.x & 63) == 0) reds[threadIdx.x >> 6] = sum;
    __syncthreads();
    const float inv = 1.f / (reds[0] + reds[1] + reds[2] + reds[3]);

    for (int t = threadIdx.x; t < T; t += TPB)
        weights[(size_t)b * T + t] = __expf(s[t] - m) * inv;
}

// ---------------------------------------------------------------- K6: partial expectation (16 chunks of 128 t)
__global__ void k_exp_partial(const float* __restrict__ X, const float* __restrict__ wts,
                              float* __restrict__ part) {
    const int b = blockIdx.x >> 4;
    const int c = blockIdx.x & 15;
    const int t0 = c * 128;
    const int d0 = threadIdx.x * 4;   // 128 threads x float4
    const float* Xb = X + ((size_t)b * T + t0) * D + d0;
    const float* wb = wts + (size_t)b * T + t0;
    float4 a = {0.f, 0.f, 0.f, 0.f};
    for (int t = 0; t < 128; ++t) {
        const float wgt = wb[t];
        const float4 x = *(const float4*)(Xb + (size_t)t * D);
        a.x += wgt * x.x; a.y += wgt * x.y; a.z += wgt * x.z; a.w += wgt * x.w;
    }
    *(float4*)(part + ((size_t)(b * 16 + c)) * D + d0) = a;
}

// ---------------------------------------------------------------- K7: reduce 16 partials
__global__ void k_exp_reduce(const float* __restrict__ part, float* __restrict__ out) {
    const int i = blockIdx.x * TPB + threadIdx.x;   // B*D
    const int b = i >> 9, d = i & 511;
    float a = 0.f;
#pragma unroll
    for (int c = 0; c < 16; ++c) a += part[((size_t)(b * 16 + c)) * D + d];
    out[i] = a;
}

// ----------------------------------------------------------------
extern "C" void kernel_launch(void* const* d_in, const int* in_sizes, int n_in,
                              void* d_out, int out_size, void* d_ws, size_t ws_size,
                              hipStream_t stream) {
    const float* X      = (const float*)d_in[0];
    const float* query  = (const float*)d_in[1];
    const int*   len    = (const int*)  d_in[2];
    const float* w      = (const float*)d_in[3];
    const float* u      = (const float*)d_in[4];
    const float* v      = (const float*)d_in[5];

    float* out     = (float*)d_out;
    float* score   = out;
    float* weights = out + (size_t)B * T;
    float* expec   = out + (size_t)2 * B * T;

    // ws layout: uq 64K | partialS 1M | WhF 512K | WlF 512K  (~2.1 MB)
    float* uq       = (float*)d_ws;
    float* partialS = uq + (size_t)B * D;                       // 262144 floats
    uint4* WhF      = (uint4*)(partialS + (size_t)4 * NROW);    // 32768 uint4
    uint4* WlF      = WhF + 32768;
    float* part     = partialS;   // alias: 16*B*D floats = 1MB, partialS dead by then

    k_uq         <<<B,            TPB, 0, stream>>>(query, u, uq);
    k_convW      <<<128,          TPB, 0, stream>>>(w, WhF, WlF);
    k_gemm       <<<2048,         TPB, 0, stream>>>(X, WhF, WlF, v, uq, partialS);
    k_combine    <<<NROW / TPB,   TPB, 0, stream>>>(partialS, len, score);
    k_softmax    <<<B,            TPB, 0, stream>>>(score, weights);
    k_exp_partial<<<B * 16,       128, 0, stream>>>(X, weights, part);
    k_exp_reduce <<<B * D / TPB,  TPB, 0, stream>>>(part, expec);
}

// Round 15
// 326.834 us; speedup vs baseline: 1.2762x; 1.2762x over previous
//
#include <hip/hip_runtime.h>
#include <math.h>

// Bahdanau attention: B=32, T=2048, D=512, Q=512, fp32.
// out = [score (B*T), weights (B*T), expectation (B*D)] concatenated.
// Masked positions: finite sentinel -1e30 (ref has -inf; |inf diff| <= inf thr,
// exp underflows to 0 identically).
//
// R15: R13 structure, kc stagger REVERTED (R14: stagger broke sibling-block
// L2 temporal locality, FETCH 88->600MB, 3x regression). New: B staged
// through LDS once per block (unique 16 KB/step vs 32 KB of per-wave L2
// transactions), single B buffer with a second LDS-only barrier; B(i+1)
// global->reg issued early, ds_written AFTER the MFMA cluster (T14: vmcnt
// wait hidden under 931 cyc of MFMA). MFMA as 3 independent passes over the
// 16 accumulators (no acc dependency stalls). 3 blocks/CU.

#define TPB 256
constexpr int B = 32, T = 2048, D = 512, Qd = 512;
constexpr int NROW = B * T;
#define NEG_SENTINEL (-1e30f)

typedef __attribute__((ext_vector_type(8))) short bf16x8;
typedef __attribute__((ext_vector_type(4))) float f32x4;

// LDS-only barrier: ds ops drained, vmem stays in flight.
__device__ __forceinline__ void lds_barrier() {
    asm volatile("s_waitcnt lgkmcnt(0)" ::: "memory");
    __builtin_amdgcn_s_barrier();
}

// HW packed fp32->bf16 RNE: result.lo16 = bf16(a), result.hi16 = bf16(b)
__device__ __forceinline__ unsigned cvtpk(float a, float b) {
    unsigned r;
    asm("v_cvt_pk_bf16_f32 %0, %1, %2" : "=v"(r) : "v"(a), "v"(b));
    return r;
}
// split two floats into packed-hi (return) and packed-lo bf16 pairs
__device__ __forceinline__ unsigned packsplit(float f0, float f1, unsigned& lopack) {
    unsigned hp = cvtpk(f0, f1);
    float h0 = __builtin_bit_cast(float, hp << 16);
    float h1 = __builtin_bit_cast(float, hp & 0xFFFF0000u);
    lopack = cvtpk(f0 - h0, f1 - h1);
    return hp;
}
__device__ __forceinline__ void cvt8(const float4 a, const float4 b, uint4& hi, uint4& lo) {
    hi.x = packsplit(a.x, a.y, lo.x);
    hi.y = packsplit(a.z, a.w, lo.y);
    hi.z = packsplit(b.x, b.y, lo.z);
    hi.w = packsplit(b.z, b.w, lo.w);
}
// fast tanh: saturating exp form, |err| ~ 1e-7
__device__ __forceinline__ float fast_tanh(float x) {
    float a = fabsf(x);
    float e = __expf(-2.f * a);
    float t = (1.f - e) / (1.f + e);
    return copysignf(t, x);
}

// ---------------------------------------------------------------- K1: uq[b][e]
__global__ void k_uq(const float* __restrict__ query, const float* __restrict__ u,
                     float* __restrict__ uq) {
    int b = blockIdx.x;
    __shared__ float q_s[Qd];
    for (int i = threadIdx.x; i < Qd; i += TPB) q_s[i] = query[b * Qd + i];
    __syncthreads();
    for (int e = threadIdx.x; e < D; e += TPB) {
        const float4* urow = (const float4*)(u + (size_t)e * Qd);
        float acc = 0.f;
        for (int q4 = 0; q4 < Qd / 4; ++q4) {
            float4 uu = urow[q4];
            float4 qq = *(const float4*)(q_s + q4 * 4);
            acc += uu.x * qq.x + uu.y * qq.y + uu.z * qq.z + uu.w * qq.w;
        }
        uq[b * D + e] = acc;
    }
}

// ---------------------------------------------------------------- K2: W -> split-bf16 fragment layout
// idx16 = ((nt*16 + kc)*8 + cb)*64 + hi4*16 + lo16
//   e = nt*128 + cb*16 + lo16, d = kc*32 + hi4*8 .. +8
__global__ void k_convW(const float* __restrict__ W,
                        uint4* __restrict__ WhF, uint4* __restrict__ WlF) {
    const int g = blockIdx.x * 256 + threadIdx.x;   // 0..32767
    const int e = g >> 6, s = g & 63;               // d0 = s*8
    const float4* src = (const float4*)(W + (size_t)e * D + s * 8);
    float4 a = src[0], bq = src[1];
    uint4 hi, lo;
    cvt8(a, bq, hi, lo);
    const int nt = e >> 7, cb = (e >> 4) & 7, lo16 = e & 15;
    const int kc = s >> 2, hi4 = s & 3;
    const size_t idx = ((size_t)(nt * 16 + kc) * 8 + cb) * 64 + hi4 * 16 + lo16;
    WhF[idx] = hi;
    WlF[idx] = lo;
}

// ---------------------------------------------------------------- K3: split-bf16 MFMA GEMM + fused tanh*v
// Block tile 128x128, BK=32, 4 waves (2m x 2n), wave 64x64 = 4x4 frags of
// 16x16x32, 3 products in fp32 acc. A: regs -> cvt_pk -> LDS double-buffer.
// B: preconverted frag-layout, staged global->reg->LDS (one copy per block),
// read by waves as frags. Two LDS-only barriers per K-step; B ds_write after
// MFMA so its vmem wait hides under the MFMA cluster. 3 blocks/CU.
__global__ __launch_bounds__(256, 3) void k_gemm(
    const float* __restrict__ X,
    const uint4* __restrict__ WhF,
    const uint4* __restrict__ WlF,
    const float* __restrict__ v,
    const float* __restrict__ uqg,
    float* __restrict__ partialS)   // [4][NROW]
{
    __shared__ uint4 Ah[2][4 * 128], Al[2][4 * 128];   // 32 KB
    __shared__ uint4 Bh[8 * 64], Bl[8 * 64];           // 16 KB
    __shared__ float scr[2][128];

    // XCD-bijective swizzle (2048 % 8 == 0)
    const int gidx = blockIdx.x;
    const int logical = (gidx & 7) * 256 + (gidx >> 3);
    const int mt = logical >> 2, nt = logical & 3;
    const int row0 = mt * 128, e0 = nt * 128;
    const int b = row0 >> 11;

    const int tid = threadIdx.x, lane = tid & 63, wid = tid >> 6;
    const int wm = wid >> 1, wn = wid & 1;
    const int lo16 = lane & 15, hi4 = lane >> 4;
    const int arow = tid & 127, akh = tid >> 7;

    const float4* Xg = (const float4*)(X + (size_t)(row0 + arow) * D + akh * 16);
    // B staging source: for kc, 512 contiguous uint4 starting at (nt*16+kc)*8*64
    const uint4* WhS = WhF + ((size_t)nt * 16) * 8 * 64 + tid;
    const uint4* WlS = WlF + ((size_t)nt * 16) * 8 * 64 + tid;

    f32x4 acc[4][4];
#pragma unroll
    for (int i = 0; i < 4; ++i)
#pragma unroll
        for (int j = 0; j < 4; ++j) acc[i][j] = (f32x4){0.f, 0.f, 0.f, 0.f};

    // prologue: X(0)->xr[0], X(1)->xr[1]; B(0)->regs; convert X(0)->A[0]; B(0)->LDS
    float4 xr[2][4];
#pragma unroll
    for (int i = 0; i < 4; ++i) xr[0][i] = Xg[i];
#pragma unroll
    for (int i = 0; i < 4; ++i) xr[1][i] = Xg[8 + i];
    uint4 bs0, bs1, bs2, bs3;   // B stage regs: Bh[tid], Bh[tid+256], Bl[tid], Bl[tid+256]
    bs0 = WhS[0];  bs1 = WhS[256];
    bs2 = WlS[0];  bs3 = WlS[256];
    {
        uint4 hp, lp;
        cvt8(xr[0][0], xr[0][1], hp, lp);
        Ah[0][(akh * 2 + 0) * 128 + arow] = hp;
        Al[0][(akh * 2 + 0) * 128 + arow] = lp;
        cvt8(xr[0][2], xr[0][3], hp, lp);
        Ah[0][(akh * 2 + 1) * 128 + arow] = hp;
        Al[0][(akh * 2 + 1) * 128 + arow] = lp;
    }
    Bh[tid] = bs0;  Bh[tid + 256] = bs1;
    Bl[tid] = bs2;  Bl[tid + 256] = bs3;

#pragma unroll
    for (int kc = 0; kc < 16; ++kc) {
        const int cur = kc & 1, nxt = cur ^ 1;
        lds_barrier();   // barA: A(kc) in A[cur], B(kc) in Bh/Bl all visible

        // frag reads: A from A[cur], B from Bh/Bl  (16x ds_read_b128, conflict-free)
        bf16x8 aH[4], aL[4], bH[4], bL[4];
#pragma unroll
        for (int fr = 0; fr < 4; ++fr) {
            const int idx = hi4 * 128 + wm * 64 + fr * 16 + lo16;
            aH[fr] = __builtin_bit_cast(bf16x8, Ah[cur][idx]);
            aL[fr] = __builtin_bit_cast(bf16x8, Al[cur][idx]);
        }
#pragma unroll
        for (int fc = 0; fc < 4; ++fc) {
            const int idx = (wn * 4 + fc) * 64 + lane;
            bH[fc] = __builtin_bit_cast(bf16x8, Bh[idx]);
            bL[fc] = __builtin_bit_cast(bf16x8, Bl[idx]);
        }

        // issue B(kc+1) stage loads (oldest in vmem queue), then X(kc+2)
        if (kc + 1 < 16) {
            const uint4* wh = WhS + (size_t)(kc + 1) * 512;
            const uint4* wl = WlS + (size_t)(kc + 1) * 512;
            bs0 = wh[0];  bs1 = wh[256];
            bs2 = wl[0];  bs3 = wl[256];
        }
        if (kc + 2 < 16) {
#pragma unroll
            for (int i = 0; i < 4; ++i) xr[cur][i] = Xg[(kc + 2) * 8 + i];
        }

        // convert X(kc+1) -> ds_write A[nxt] (A[nxt] fully read by barA above)
        if (kc + 1 < 16) {
            uint4 hp, lp;
            cvt8(xr[nxt][0], xr[nxt][1], hp, lp);
            Ah[nxt][(akh * 2 + 0) * 128 + arow] = hp;
            Al[nxt][(akh * 2 + 0) * 128 + arow] = lp;
            cvt8(xr[nxt][2], xr[nxt][3], hp, lp);
            Ah[nxt][(akh * 2 + 1) * 128 + arow] = hp;
            Al[nxt][(akh * 2 + 1) * 128 + arow] = lp;
        }

        lds_barrier();   // barB: all waves' A/B frag reads complete -> Bbuf reusable

        // MFMA: 3 independent passes over 16 accumulators (no dep stalls)
        __builtin_amdgcn_s_setprio(1);
#pragma unroll
        for (int fc = 0; fc < 4; ++fc)
#pragma unroll
            for (int fr = 0; fr < 4; ++fr)
                acc[fr][fc] = __builtin_amdgcn_mfma_f32_16x16x32_bf16(aH[fr], bH[fc], acc[fr][fc], 0, 0, 0);
#pragma unroll
        for (int fc = 0; fc < 4; ++fc)
#pragma unroll
            for (int fr = 0; fr < 4; ++fr)
                acc[fr][fc] = __builtin_amdgcn_mfma_f32_16x16x32_bf16(aH[fr], bL[fc], acc[fr][fc], 0, 0, 0);
#pragma unroll
        for (int fc = 0; fc < 4; ++fc)
#pragma unroll
            for (int fr = 0; fr < 4; ++fr)
                acc[fr][fc] = __builtin_amdgcn_mfma_f32_16x16x32_bf16(aL[fr], bH[fc], acc[fr][fc], 0, 0, 0);
        __builtin_amdgcn_s_setprio(0);

        // B(kc+1) -> LDS (vmcnt wait was hidden under the MFMA cluster)
        if (kc + 1 < 16) {
            Bh[tid] = bs0;  Bh[tid + 256] = bs1;
            Bl[tid] = bs2;  Bl[tid + 256] = bs3;
        }
    }

    // ---- epilogue: p[row] = sum_col tanh(acc + uq[col]) * v[col]
    const int colbase = e0 + wn * 64;
#pragma unroll
    for (int fr = 0; fr < 4; ++fr) {
        float ps[4] = {0.f, 0.f, 0.f, 0.f};
#pragma unroll
        for (int fc = 0; fc < 4; ++fc) {
            const int col = colbase + fc * 16 + lo16;
            const float uqc = uqg[b * D + col];
            const float vc  = v[col];
#pragma unroll
            for (int i = 0; i < 4; ++i)
                ps[i] += fast_tanh(acc[fr][fc][i] + uqc) * vc;
        }
#pragma unroll
        for (int i = 0; i < 4; ++i) {
            float p = ps[i];
#pragma unroll
            for (int off = 8; off >= 1; off >>= 1) p += __shfl_xor(p, off, 16);
            if (lo16 == 0) scr[wn][wm * 64 + fr * 16 + hi4 * 4 + i] = p;
        }
    }
    __syncthreads();
    if (tid < 128)
        partialS[(size_t)nt * NROW + row0 + tid] = scr[0][tid] + scr[1][tid];
}

// ---------------------------------------------------------------- K4: combine 4 partials + mask
__global__ void k_combine(const float* __restrict__ partialS,
                          const int* __restrict__ lengths,
                          float* __restrict__ score) {
    const int i = blockIdx.x * TPB + threadIdx.x;
    const int b = i >> 11, t = i & (T - 1);
    float s = partialS[i] + partialS[NROW + i] + partialS[2 * NROW + i] + partialS[3 * NROW + i];
    score[i] = (t < lengths[b]) ? s : NEG_SENTINEL;
}

// ---------------------------------------------------------------- K5: softmax over t per batch
__global__ void k_softmax(const float* __restrict__ score, float* __restrict__ weights) {
    const int b = blockIdx.x;
    const float* s = score + (size_t)b * T;
    float m = -INFINITY;
    for (int t = threadIdx.x; t < T; t += TPB) m = fmaxf(m, s[t]);
#pragma unroll
    for (int off = 32; off >= 1; off >>= 1) m = fmaxf(m, __shfl_xor(m, off, 64));
    __shared__ float redm[4];
    if ((threadIdx.x & 63) == 0) redm[threadIdx.x >> 6] = m;
    __syncthreads();
    m = fmaxf(fmaxf(redm[0], redm[1]), fmaxf(redm[2], redm[3]));

    float sum = 0.f;
    for (int t = threadIdx.x; t < T; t += TPB) sum += __expf(s[t] - m);
#pragma unroll
    for (int off = 32; off >= 1; off >>= 1) sum += __shfl_xor(sum, off, 64);
    __shared__ float reds[4];
    if ((threadIdx.x & 63) == 0) reds[threadIdx.x >> 6] = sum;
    __syncthreads();
    const float inv = 1.f / (reds[0] + reds[1] + reds[2] + reds[3]);

    for (int t = threadIdx.x; t < T; t += TPB)
        weights[(size_t)b * T + t] = __expf(s[t] - m) * inv;
}

// ---------------------------------------------------------------- K6: partial expectation (16 chunks of 128 t)
__global__ void k_exp_partial(const float* __restrict__ X, const float* __restrict__ wts,
                              float* __restrict__ part) {
    const int b = blockIdx.x >> 4;
    const int c = blockIdx.x & 15;
    const int t0 = c * 128;
    const int d0 = threadIdx.x * 4;   // 128 threads x float4
    const float* Xb = X + ((size_t)b * T + t0) * D + d0;
    const float* wb = wts + (size_t)b * T + t0;
    float4 a = {0.f, 0.f, 0.f, 0.f};
    for (int t = 0; t < 128; ++t) {
        const float wgt = wb[t];
        const float4 x = *(const float4*)(Xb + (size_t)t * D);
        a.x += wgt * x.x; a.y += wgt * x.y; a.z += wgt * x.z; a.w += wgt * x.w;
    }
    *(float4*)(part + ((size_t)(b * 16 + c)) * D + d0) = a;
}

// ---------------------------------------------------------------- K7: reduce 16 partials
__global__ void k_exp_reduce(const float* __restrict__ part, float* __restrict__ out) {
    const int i = blockIdx.x * TPB + threadIdx.x;   // B*D
    const int b = i >> 9, d = i & 511;
    float a = 0.f;
#pragma unroll
    for (int c = 0; c < 16; ++c) a += part[((size_t)(b * 16 + c)) * D + d];
    out[i] = a;
}

// ----------------------------------------------------------------
extern "C" void kernel_launch(void* const* d_in, const int* in_sizes, int n_in,
                              void* d_out, int out_size, void* d_ws, size_t ws_size,
                              hipStream_t stream) {
    const float* X      = (const float*)d_in[0];
    const float* query  = (const float*)d_in[1];
    const int*   len    = (const int*)  d_in[2];
    const float* w      = (const float*)d_in[3];
    const float* u      = (const float*)d_in[4];
    const float* v      = (const float*)d_in[5];

    float* out     = (float*)d_out;
    float* score   = out;
    float* weights = out + (size_t)B * T;
    float* expec   = out + (size_t)2 * B * T;

    // ws layout: uq 64K | partialS 1M | WhF 512K | WlF 512K  (~2.1 MB)
    float* uq       = (float*)d_ws;
    float* partialS = uq + (size_t)B * D;                       // 262144 floats
    uint4* WhF      = (uint4*)(partialS + (size_t)4 * NROW);    // 32768 uint4
    uint4* WlF      = WhF + 32768;
    float* part     = partialS;   // alias: 16*B*D floats = 1MB, partialS dead by then

    k_uq         <<<B,            TPB, 0, stream>>>(query, u, uq);
    k_convW      <<<128,          TPB, 0, stream>>>(w, WhF, WlF);
    k_gemm       <<<2048,         TPB, 0, stream>>>(X, WhF, WlF, v, uq, partialS);
    k_combine    <<<NROW / TPB,   TPB, 0, stream>>>(partialS, len, score);
    k_softmax    <<<B,            TPB, 0, stream>>>(score, weights);
    k_exp_partial<<<B * 16,       128, 0, stream>>>(X, weights, part);
    k_exp_reduce <<<B * D / TPB,  TPB, 0, stream>>>(part, expec);
}

// Round 16
// 205.935 us; speedup vs baseline: 2.0254x; 1.5871x over previous
//
#include <hip/hip_runtime.h>
#include <math.h>

// Bahdanau attention: B=32, T=2048, D=512, Q=512, fp32.
// out = [score (B*T), weights (B*T), expectation (B*D)] concatenated.
// Masked positions: finite sentinel -1e30 (ref has -inf; |inf diff| <= inf thr,
// exp underflows to 0 identically).
//
// R16: PRECONVERTED-X streaming GEMM (if ws_size permits, ~130 MB):
// X is converted once to fragment-layout split-bf16 (like W). The GEMM then
// has NO LDS staging, NO barriers, NO in-loop conversion -- pure coalesced
// frag loads (1 KB/wave-instr) + MFMA with 1-step register double-buffer.
// This fixes R10's failure (uncoalesced A loads from row-major X) by owning
// the layout. Fallback (small ws): R13 kernel verbatim (163 us, known-good).
// R15's B-LDS variant REVERTED (register spill -> 614 MB scratch writes).

#define TPB 256
constexpr int B = 32, T = 2048, D = 512, Qd = 512;
constexpr int NROW = B * T;
#define NEG_SENTINEL (-1e30f)

typedef __attribute__((ext_vector_type(8))) short bf16x8;
typedef __attribute__((ext_vector_type(4))) float f32x4;

// LDS-only barrier: ds ops drained, vmem stays in flight.
__device__ __forceinline__ void lds_barrier() {
    asm volatile("s_waitcnt lgkmcnt(0)" ::: "memory");
    __builtin_amdgcn_s_barrier();
}

// HW packed fp32->bf16 RNE: result.lo16 = bf16(a), result.hi16 = bf16(b)
__device__ __forceinline__ unsigned cvtpk(float a, float b) {
    unsigned r;
    asm("v_cvt_pk_bf16_f32 %0, %1, %2" : "=v"(r) : "v"(a), "v"(b));
    return r;
}
// split two floats into packed-hi (return) and packed-lo bf16 pairs
__device__ __forceinline__ unsigned packsplit(float f0, float f1, unsigned& lopack) {
    unsigned hp = cvtpk(f0, f1);
    float h0 = __builtin_bit_cast(float, hp << 16);
    float h1 = __builtin_bit_cast(float, hp & 0xFFFF0000u);
    lopack = cvtpk(f0 - h0, f1 - h1);
    return hp;
}
__device__ __forceinline__ void cvt8(const float4 a, const float4 b, uint4& hi, uint4& lo) {
    hi.x = packsplit(a.x, a.y, lo.x);
    hi.y = packsplit(a.z, a.w, lo.y);
    hi.z = packsplit(b.x, b.y, lo.z);
    hi.w = packsplit(b.z, b.w, lo.w);
}
// fast tanh: saturating exp form, |err| ~ 1e-7
__device__ __forceinline__ float fast_tanh(float x) {
    float a = fabsf(x);
    float e = __expf(-2.f * a);
    float t = (1.f - e) / (1.f + e);
    return copysignf(t, x);
}

// ---------------------------------------------------------------- K1: uq[b][e]
__global__ void k_uq(const float* __restrict__ query, const float* __restrict__ u,
                     float* __restrict__ uq) {
    int b = blockIdx.x;
    __shared__ float q_s[Qd];
    for (int i = threadIdx.x; i < Qd; i += TPB) q_s[i] = query[b * Qd + i];
    __syncthreads();
    for (int e = threadIdx.x; e < D; e += TPB) {
        const float4* urow = (const float4*)(u + (size_t)e * Qd);
        float acc = 0.f;
        for (int q4 = 0; q4 < Qd / 4; ++q4) {
            float4 uu = urow[q4];
            float4 qq = *(const float4*)(q_s + q4 * 4);
            acc += uu.x * qq.x + uu.y * qq.y + uu.z * qq.z + uu.w * qq.w;
        }
        uq[b * D + e] = acc;
    }
}

// ---------------------------------------------------------------- K2: W -> split-bf16 fragment layout
// idx16 = ((nt*16 + kc)*8 + cb)*64 + hi4*16 + lo16
//   e = nt*128 + cb*16 + lo16, d = kc*32 + hi4*8 .. +8
__global__ void k_convW(const float* __restrict__ W,
                        uint4* __restrict__ WhF, uint4* __restrict__ WlF) {
    const int g = blockIdx.x * 256 + threadIdx.x;   // 0..32767
    const int e = g >> 6, s = g & 63;               // d0 = s*8
    const float4* src = (const float4*)(W + (size_t)e * D + s * 8);
    float4 a = src[0], bq = src[1];
    uint4 hi, lo;
    cvt8(a, bq, hi, lo);
    const int nt = e >> 7, cb = (e >> 4) & 7, lo16 = e & 15;
    const int kc = s >> 2, hi4 = s & 3;
    const size_t idx = ((size_t)(nt * 16 + kc) * 8 + cb) * 64 + hi4 * 16 + lo16;
    WhF[idx] = hi;
    WlF[idx] = lo;
}

// ---------------------------------------------------------------- K2b: X -> split-bf16 fragment layout
// Thread g writes XhF[g]/XlF[g] (perfectly coalesced). Inverse map:
//   lo16=g&15, hi4=(g>>4)&3, rb=(g>>6)&7, kc=(g>>9)&15, mt=g>>13
//   row = mt*128 + rb*16 + lo16 ; d0 = kc*32 + hi4*8
// A wave covers 16 rows x 128 B contiguous source each -> coalesced reads.
__global__ void k_convX(const float* __restrict__ X,
                        uint4* __restrict__ XhF, uint4* __restrict__ XlF) {
    const int g = blockIdx.x * 256 + threadIdx.x;   // 0..NROW*64-1
    const int lo16 = g & 15, hi4 = (g >> 4) & 3, rb = (g >> 6) & 7;
    const int kc = (g >> 9) & 15, mt = g >> 13;
    const int row = mt * 128 + rb * 16 + lo16;
    const int d0 = kc * 32 + hi4 * 8;
    const float4* src = (const float4*)(X + (size_t)row * D + d0);
    float4 a = src[0], bq = src[1];
    uint4 hi, lo;
    cvt8(a, bq, hi, lo);
    XhF[g] = hi;
    XlF[g] = lo;
}

// ---------------------------------------------------------------- K3a: STREAMING split-bf16 MFMA GEMM (fast path)
// Block 128x128, 4 waves (2m x 2n), wave 64x64 = 4x4 frags of 16x16x32.
// Both operands preconverted frag-layout: global->reg, coalesced, no LDS,
// no barriers in the K-loop. 1-step register double-buffer (compile-time
// indices via full unroll). 3 MFMA products in fp32 acc.
__global__ __launch_bounds__(256, 2) void k_gemm_stream(
    const uint4* __restrict__ XhF, const uint4* __restrict__ XlF,
    const uint4* __restrict__ WhF, const uint4* __restrict__ WlF,
    const float* __restrict__ v,
    const float* __restrict__ uqg,
    float* __restrict__ partialS)   // [4][NROW]
{
    __shared__ float scr[2][128];

    // XCD-bijective swizzle (2048 % 8 == 0)
    const int gidx = blockIdx.x;
    const int logical = (gidx & 7) * 256 + (gidx >> 3);
    const int mt = logical >> 2, nt = logical & 3;
    const int row0 = mt * 128, e0 = nt * 128;
    const int b = row0 >> 11;

    const int tid = threadIdx.x, lane = tid & 63, wid = tid >> 6;
    const int wm = wid >> 1, wn = wid & 1;
    const int lo16 = lane & 15, hi4 = lane >> 4;

    const uint4* XhB = XhF + ((size_t)mt * 16) * 8 * 64 + (wm * 4) * 64 + lane;
    const uint4* XlB = XlF + ((size_t)mt * 16) * 8 * 64 + (wm * 4) * 64 + lane;
    const uint4* WhB = WhF + ((size_t)nt * 16) * 8 * 64 + (wn * 4) * 64 + lane;
    const uint4* WlB = WlF + ((size_t)nt * 16) * 8 * 64 + (wn * 4) * 64 + lane;

    f32x4 acc[4][4];
#pragma unroll
    for (int i = 0; i < 4; ++i)
#pragma unroll
        for (int j = 0; j < 4; ++j) acc[i][j] = (f32x4){0.f, 0.f, 0.f, 0.f};

    uint4 ah[2][4], al[2][4], bh[2][4], bl[2][4];
    // prologue: step 0 frags
#pragma unroll
    for (int f = 0; f < 4; ++f) {
        ah[0][f] = XhB[f * 64];
        al[0][f] = XlB[f * 64];
        bh[0][f] = WhB[f * 64];
        bl[0][f] = WlB[f * 64];
    }

#pragma unroll
    for (int kc = 0; kc < 16; ++kc) {
        const int cur = kc & 1, nxt = cur ^ 1;
        // issue next-step loads first (16 loads in flight across the MFMAs)
        if (kc + 1 < 16) {
            const size_t off = (size_t)(kc + 1) * 512;
#pragma unroll
            for (int f = 0; f < 4; ++f) {
                ah[nxt][f] = XhB[off + f * 64];
                al[nxt][f] = XlB[off + f * 64];
                bh[nxt][f] = WhB[off + f * 64];
                bl[nxt][f] = WlB[off + f * 64];
            }
        }
        // 48 MFMA on current frags (compiler waits vmcnt(16) for cur only)
#pragma unroll
        for (int fc = 0; fc < 4; ++fc) {
            const bf16x8 bH = __builtin_bit_cast(bf16x8, bh[cur][fc]);
            const bf16x8 bL = __builtin_bit_cast(bf16x8, bl[cur][fc]);
#pragma unroll
            for (int fr = 0; fr < 4; ++fr) {
                const bf16x8 aH = __builtin_bit_cast(bf16x8, ah[cur][fr]);
                const bf16x8 aL = __builtin_bit_cast(bf16x8, al[cur][fr]);
                acc[fr][fc] = __builtin_amdgcn_mfma_f32_16x16x32_bf16(aH, bH, acc[fr][fc], 0, 0, 0);
                acc[fr][fc] = __builtin_amdgcn_mfma_f32_16x16x32_bf16(aH, bL, acc[fr][fc], 0, 0, 0);
                acc[fr][fc] = __builtin_amdgcn_mfma_f32_16x16x32_bf16(aL, bH, acc[fr][fc], 0, 0, 0);
            }
        }
    }

    // ---- epilogue: p[row] = sum_col tanh(acc + uq[col]) * v[col]
    const int colbase = e0 + wn * 64;
#pragma unroll
    for (int fr = 0; fr < 4; ++fr) {
        float ps[4] = {0.f, 0.f, 0.f, 0.f};
#pragma unroll
        for (int fc = 0; fc < 4; ++fc) {
            const int col = colbase + fc * 16 + lo16;
            const float uqc = uqg[b * D + col];
            const float vc  = v[col];
#pragma unroll
            for (int i = 0; i < 4; ++i)
                ps[i] += fast_tanh(acc[fr][fc][i] + uqc) * vc;
        }
#pragma unroll
        for (int i = 0; i < 4; ++i) {
            float p = ps[i];
#pragma unroll
            for (int off = 8; off >= 1; off >>= 1) p += __shfl_xor(p, off, 16);
            if (lo16 == 0) scr[wn][wm * 64 + fr * 16 + hi4 * 4 + i] = p;
        }
    }
    __syncthreads();
    if (tid < 128)
        partialS[(size_t)nt * NROW + row0 + tid] = scr[0][tid] + scr[1][tid];
}

// ---------------------------------------------------------------- K3b: fallback GEMM (R13 verbatim, 163 us known-good)
__global__ __launch_bounds__(256, 4) void k_gemm(
    const float* __restrict__ X,
    const uint4* __restrict__ WhF,
    const uint4* __restrict__ WlF,
    const float* __restrict__ v,
    const float* __restrict__ uqg,
    float* __restrict__ partialS)   // [4][NROW]
{
    __shared__ uint4 Ah[2][4 * 128], Al[2][4 * 128];   // 32 KB
    __shared__ float scr[2][128];

    const int gidx = blockIdx.x;
    const int logical = (gidx & 7) * 256 + (gidx >> 3);
    const int mt = logical >> 2, nt = logical & 3;
    const int row0 = mt * 128, e0 = nt * 128;
    const int b = row0 >> 11;

    const int tid = threadIdx.x, lane = tid & 63, wid = tid >> 6;
    const int wm = wid >> 1, wn = wid & 1;
    const int lo16 = lane & 15, hi4 = lane >> 4;
    const int arow = tid & 127, akh = tid >> 7;

    const float4* Xg = (const float4*)(X + (size_t)(row0 + arow) * D + akh * 16);
    const uint4* WhB = WhF + ((size_t)nt * 16) * 8 * 64 + (wn * 4) * 64 + lane;
    const uint4* WlB = WlF + ((size_t)nt * 16) * 8 * 64 + (wn * 4) * 64 + lane;

    f32x4 acc[4][4];
#pragma unroll
    for (int i = 0; i < 4; ++i)
#pragma unroll
        for (int j = 0; j < 4; ++j) acc[i][j] = (f32x4){0.f, 0.f, 0.f, 0.f};

    float4 xr[2][4];
#pragma unroll
    for (int i = 0; i < 4; ++i) xr[0][i] = Xg[i];
#pragma unroll
    for (int i = 0; i < 4; ++i) xr[1][i] = Xg[8 + i];
    {
        uint4 hp, lp;
        cvt8(xr[0][0], xr[0][1], hp, lp);
        Ah[0][(akh * 2 + 0) * 128 + arow] = hp;
        Al[0][(akh * 2 + 0) * 128 + arow] = lp;
        cvt8(xr[0][2], xr[0][3], hp, lp);
        Ah[0][(akh * 2 + 1) * 128 + arow] = hp;
        Al[0][(akh * 2 + 1) * 128 + arow] = lp;
    }

#pragma unroll
    for (int kc = 0; kc < 16; ++kc) {
        const int cur = kc & 1, nxt = cur ^ 1;
        lds_barrier();

        uint4 bhr[4], blr[4];
        {
            const uint4* wh = WhB + (size_t)kc * 8 * 64;
            const uint4* wl = WlB + (size_t)kc * 8 * 64;
#pragma unroll
            for (int fc = 0; fc < 4; ++fc) {
                bhr[fc] = wh[fc * 64];
                blr[fc] = wl[fc * 64];
            }
        }

        if (kc + 1 < 16) {
            uint4 hp, lp;
            cvt8(xr[nxt][0], xr[nxt][1], hp, lp);
            Ah[nxt][(akh * 2 + 0) * 128 + arow] = hp;
            Al[nxt][(akh * 2 + 0) * 128 + arow] = lp;
            cvt8(xr[nxt][2], xr[nxt][3], hp, lp);
            Ah[nxt][(akh * 2 + 1) * 128 + arow] = hp;
            Al[nxt][(akh * 2 + 1) * 128 + arow] = lp;
        }

        bf16x8 aH[4], aL[4];
#pragma unroll
        for (int fr = 0; fr < 4; ++fr) {
            const int idx = hi4 * 128 + wm * 64 + fr * 16 + lo16;
            aH[fr] = __builtin_bit_cast(bf16x8, Ah[cur][idx]);
            aL[fr] = __builtin_bit_cast(bf16x8, Al[cur][idx]);
        }

#pragma unroll
        for (int fc = 0; fc < 4; ++fc) {
            const bf16x8 bH = __builtin_bit_cast(bf16x8, bhr[fc]);
            const bf16x8 bL = __builtin_bit_cast(bf16x8, blr[fc]);
#pragma unroll
            for (int fr = 0; fr < 4; ++fr) {
                acc[fr][fc] = __builtin_amdgcn_mfma_f32_16x16x32_bf16(aH[fr], bH, acc[fr][fc], 0, 0, 0);
                acc[fr][fc] = __builtin_amdgcn_mfma_f32_16x16x32_bf16(aH[fr], bL, acc[fr][fc], 0, 0, 0);
                acc[fr][fc] = __builtin_amdgcn_mfma_f32_16x16x32_bf16(aL[fr], bH, acc[fr][fc], 0, 0, 0);
            }
        }

        if (kc + 2 < 16) {
#pragma unroll
            for (int i = 0; i < 4; ++i) xr[cur][i] = Xg[(kc + 2) * 8 + i];
        }
    }

    const int colbase = e0 + wn * 64;
#pragma unroll
    for (int fr = 0; fr < 4; ++fr) {
        float ps[4] = {0.f, 0.f, 0.f, 0.f};
#pragma unroll
        for (int fc = 0; fc < 4; ++fc) {
            const int col = colbase + fc * 16 + lo16;
            const float uqc = uqg[b * D + col];
            const float vc  = v[col];
#pragma unroll
            for (int i = 0; i < 4; ++i)
                ps[i] += fast_tanh(acc[fr][fc][i] + uqc) * vc;
        }
#pragma unroll
        for (int i = 0; i < 4; ++i) {
            float p = ps[i];
#pragma unroll
            for (int off = 8; off >= 1; off >>= 1) p += __shfl_xor(p, off, 16);
            if (lo16 == 0) scr[wn][wm * 64 + fr * 16 + hi4 * 4 + i] = p;
        }
    }
    __syncthreads();
    if (tid < 128)
        partialS[(size_t)nt * NROW + row0 + tid] = scr[0][tid] + scr[1][tid];
}

// ---------------------------------------------------------------- K4: combine 4 partials + mask
__global__ void k_combine(const float* __restrict__ partialS,
                          const int* __restrict__ lengths,
                          float* __restrict__ score) {
    const int i = blockIdx.x * TPB + threadIdx.x;
    const int b = i >> 11, t = i & (T - 1);
    float s = partialS[i] + partialS[NROW + i] + partialS[2 * NROW + i] + partialS[3 * NROW + i];
    score[i] = (t < lengths[b]) ? s : NEG_SENTINEL;
}

// ---------------------------------------------------------------- K5: softmax over t per batch
__global__ void k_softmax(const float* __restrict__ score, float* __restrict__ weights) {
    const int b = blockIdx.x;
    const float* s = score + (size_t)b * T;
    float m = -INFINITY;
    for (int t = threadIdx.x; t < T; t += TPB) m = fmaxf(m, s[t]);
#pragma unroll
    for (int off = 32; off >= 1; off >>= 1) m = fmaxf(m, __shfl_xor(m, off, 64));
    __shared__ float redm[4];
    if ((threadIdx.x & 63) == 0) redm[threadIdx.x >> 6] = m;
    __syncthreads();
    m = fmaxf(fmaxf(redm[0], redm[1]), fmaxf(redm[2], redm[3]));

    float sum = 0.f;
    for (int t = threadIdx.x; t < T; t += TPB) sum += __expf(s[t] - m);
#pragma unroll
    for (int off = 32; off >= 1; off >>= 1) sum += __shfl_xor(sum, off, 64);
    __shared__ float reds[4];
    if ((threadIdx.x & 63) == 0) reds[threadIdx.x >> 6] = sum;
    __syncthreads();
    const float inv = 1.f / (reds[0] + reds[1] + reds[2] + reds[3]);

    for (int t = threadIdx.x; t < T; t += TPB)
        weights[(size_t)b * T + t] = __expf(s[t] - m) * inv;
}

// ---------------------------------------------------------------- K6: partial expectation (16 chunks of 128 t)
__global__ void k_exp_partial(const float* __restrict__ X, const float* __restrict__ wts,
                              float* __restrict__ part) {
    const int b = blockIdx.x >> 4;
    const int c = blockIdx.x & 15;
    const int t0 = c * 128;
    const int d0 = threadIdx.x * 4;   // 128 threads x float4
    const float* Xb = X + ((size_t)b * T + t0) * D + d0;
    const float* wb = wts + (size_t)b * T + t0;
    float4 a = {0.f, 0.f, 0.f, 0.f};
    for (int t = 0; t < 128; ++t) {
        const float wgt = wb[t];
        const float4 x = *(const float4*)(Xb + (size_t)t * D);
        a.x += wgt * x.x; a.y += wgt * x.y; a.z += wgt * x.z; a.w += wgt * x.w;
    }
    *(float4*)(part + ((size_t)(b * 16 + c)) * D + d0) = a;
}

// ---------------------------------------------------------------- K7: reduce 16 partials
__global__ void k_exp_reduce(const float* __restrict__ part, float* __restrict__ out) {
    const int i = blockIdx.x * TPB + threadIdx.x;   // B*D
    const int b = i >> 9, d = i & 511;
    float a = 0.f;
#pragma unroll
    for (int c = 0; c < 16; ++c) a += part[((size_t)(b * 16 + c)) * D + d];
    out[i] = a;
}

// ----------------------------------------------------------------
extern "C" void kernel_launch(void* const* d_in, const int* in_sizes, int n_in,
                              void* d_out, int out_size, void* d_ws, size_t ws_size,
                              hipStream_t stream) {
    const float* X      = (const float*)d_in[0];
    const float* query  = (const float*)d_in[1];
    const int*   len    = (const int*)  d_in[2];
    const float* w      = (const float*)d_in[3];
    const float* u      = (const float*)d_in[4];
    const float* v      = (const float*)d_in[5];

    float* out     = (float*)d_out;
    float* score   = out;
    float* weights = out + (size_t)B * T;
    float* expec   = out + (size_t)2 * B * T;

    // ws layout (bytes):
    //   uq       : B*D*4                = 65,536
    //   partialS : 4*NROW*4             = 1,048,576   (aliased later by 'part', 1 MB)
    //   WhF/WlF  : 32768*16 each        = 524,288 x2
    //   XhF/XlF  : NROW*64*16 each      = 67,108,864 x2   (fast path only)
    float* uq       = (float*)d_ws;
    float* partialS = uq + (size_t)B * D;
    uint4* WhF      = (uint4*)(partialS + (size_t)4 * NROW);
    uint4* WlF      = WhF + 32768;
    uint4* XhF      = WlF + 32768;
    uint4* XlF      = XhF + (size_t)NROW * 64;
    float* part     = partialS;

    const size_t WS_FAST = (size_t)65536 + 1048576 + 2 * 524288 + 2 * 67108864;
    const bool fast = ws_size >= WS_FAST;

    k_uq         <<<B,            TPB, 0, stream>>>(query, u, uq);
    k_convW      <<<128,          TPB, 0, stream>>>(w, WhF, WlF);
    if (fast) {
        k_convX      <<<NROW * 64 / TPB, TPB, 0, stream>>>(X, XhF, XlF);
        k_gemm_stream<<<2048,            TPB, 0, stream>>>(XhF, XlF, WhF, WlF, v, uq, partialS);
    } else {
        k_gemm       <<<2048,            TPB, 0, stream>>>(X, WhF, WlF, v, uq, partialS);
    }
    k_combine    <<<NROW / TPB,   TPB, 0, stream>>>(partialS, len, score);
    k_softmax    <<<B,            TPB, 0, stream>>>(score, weights);
    k_exp_partial<<<B * 16,       128, 0, stream>>>(X, weights, part);
    k_exp_reduce <<<B * D / TPB,  TPB, 0, stream>>>(part, expec);
}